// Round 5
// baseline (384.857 us; speedup 1.0000x reference)
//
#include <hip/hip_runtime.h>
#include <hip/hip_bf16.h>

// y = (fq_per_token(x) @ fq_per_channel(w)^T) + b
// Exact int8 factorization: y[m,n] = sx[m]*sw[n]*dot_i32(qx[m,:],qw[n,:]) + b[n]

#define K_DIM 4096
#define N_DIM 4096
#define NT (K_DIM / 128)   // 32 K-tiles of 128 bytes

typedef int v4i __attribute__((ext_vector_type(4)));

__device__ __forceinline__ void cp16(void* lds, const void* g) {
    __builtin_amdgcn_global_load_lds(
        (const __attribute__((address_space(1))) void*)g,
        (__attribute__((address_space(3))) void*)lds, 16, 0, 0);
}

// ---------------------------------------------------------------------------
// Per-row symmetric int8 fake-quant, x and w merged into one grid. UNCHANGED.
// ---------------------------------------------------------------------------
__global__ __launch_bounds__(256) void quant_rows_kernel(
    const float* __restrict__ x, const float* __restrict__ w, int M,
    char* __restrict__ qx, char* __restrict__ qw,
    float* __restrict__ sx, float* __restrict__ sw) {
    const int blk = blockIdx.x;
    const bool is_x = blk < M;
    const int row = is_x ? blk : blk - M;
    const float* rp = (is_x ? x : w) + (size_t)row * 4096;
    char* qdst = is_x ? qx : qw;
    float* sdst = is_x ? sx : sw;

    const int tid = threadIdx.x;

    float4 v[4];
#pragma unroll
    for (int i = 0; i < 4; ++i)
        v[i] = *(const float4*)(rp + 4 * (tid + 256 * i));

    float m = 0.0f;
#pragma unroll
    for (int i = 0; i < 4; ++i) {
        m = fmaxf(m, fmaxf(fmaxf(fabsf(v[i].x), fabsf(v[i].y)),
                           fmaxf(fabsf(v[i].z), fabsf(v[i].w))));
    }
#pragma unroll
    for (int off = 32; off > 0; off >>= 1)
        m = fmaxf(m, __shfl_down(m, off));

    __shared__ float red[4];
    if ((tid & 63) == 0) red[tid >> 6] = m;
    __syncthreads();
    const float amax = fmaxf(fmaxf(red[0], red[1]), fmaxf(red[2], red[3]));
    const float scale = fmaxf(amax / 127.0f, 1e-8f);

    int* qout = (int*)(qdst + (size_t)row * 4096);
#pragma unroll
    for (int i = 0; i < 4; ++i) {
        int q0 = (int)fminf(fmaxf(rintf(v[i].x / scale), -128.0f), 127.0f);
        int q1 = (int)fminf(fmaxf(rintf(v[i].y / scale), -128.0f), 127.0f);
        int q2 = (int)fminf(fmaxf(rintf(v[i].z / scale), -128.0f), 127.0f);
        int q3 = (int)fminf(fmaxf(rintf(v[i].w / scale), -128.0f), 127.0f);
        qout[tid + 256 * i] =
            (q0 & 255) | ((q1 & 255) << 8) | ((q2 & 255) << 16) | ((q3 & 255) << 24);
    }
    if (tid == 0) sdst[row] = scale;
}

// ---------------------------------------------------------------------------
// int8 GEMM, 256x256 tile, 8 waves (2M x 4N), BK = 128 bytes.
//
// Round-5 change: ONE barrier per K-tile, no intra-tile barriers. Rounds
// 1/2/4 (4-phase counted, reg-dbuf, 2-phase) all measured ~5212 cy/tile =
// MFMA floor (2611) + LDS window (~2600) SERIALIZED: the barrier between the
// ds_read burst and the MFMA cluster aligned all 8 waves, so the CU
// alternated {all-waves-read} / {all-waves-MFMA}. The mid barrier is
// correctness-irrelevant (reads hit parity par, stages write par^1).
// Free-running waves drift within the tile -> wave i's LDS window overlaps
// wave j's MFMA window (m114 cross-wave overlap), targeting
// max(MFMA, LDS) ~ 2900-3400 cy/tile instead of the sum.
//
// Per tile t: [BAR] stage A,B(t+1)->par^1 (8 cp16) ; for ks in {0,1}:
// {12 ds_read_b128(par,ks) ; 32 MFMA} ; vmcnt(0) ; [BAR].
//   RAW: t's reads of par hit data staged in t-1 and drained by t-1's
//        vmcnt(0) before the boundary barrier.
//   WAR: stages into par^1 at top of t; par^1 was last read in t-1, and
//        those reads completed before t-1's MFMAs issued (data dep), hence
//        before the boundary barrier.
//   vmcnt(0) at end of t is ~free: only in-flight loads are t+1's stages,
//        issued a full tile (~2700 cy) earlier, needed right after the BAR.
// Compiler-safety: BAR();FENCE() and vmcnt-with-"memory" bracket the tile so
// cp16/ds_read cannot hoist above the barrier or sink below the drain
// (s_barrier alone is not a compiler memory fence). No sched pins (m141).
//
// LDS swizzle (proven, 0 conflicts): 16B chunk c of row r stored at
// c ^ (r&7); fragment read chunk = (ks*4 + lg) ^ (ln&7).
// ---------------------------------------------------------------------------
__global__ __launch_bounds__(512, 2) void gemm_i8_kernel(
    const char* __restrict__ qx, const char* __restrict__ qw,
    const float* __restrict__ sx, const float* __restrict__ sw,
    const float* __restrict__ bias, float* __restrict__ y) {

    __shared__ __align__(16) char lds[131072];

    const int tid  = threadIdx.x;
    const int wave = tid >> 6;
    const int lane = tid & 63;
    const int ln   = lane & 15;   // MFMA column index
    const int lg   = lane >> 4;   // MFMA lane-group 0..3
    const int wm   = wave >> 2;   // wave tile m (0..1) -> rows wm*128..+127
    const int wn   = wave & 3;    // wave tile n (0..3) -> cols wn*64..+63

    const int bm = blockIdx.y;
    const int bn = blockIdx.x;

    // staging: thread t handles 16B chunks t and t+512 of each 128-row half
    // (wave-contiguous LDS dest for global_load_lds); global source
    // pre-swizzled so LDS chunk (r, c) holds global k-chunk c ^ (r&7).
    const int ci0 = tid,       r0s = ci0 >> 3, c0s = (ci0 & 7) ^ (r0s & 7);
    const int ci1 = tid + 512, r1s = ci1 >> 3, c1s = (ci1 & 7) ^ (r1s & 7);
    const char* aS0 = qx + (size_t)(bm * 256 + r0s) * K_DIM + c0s * 16;
    const char* aS1 = qx + (size_t)(bm * 256 + r1s) * K_DIM + c1s * 16;
    const char* bS0 = qw + (size_t)(bn * 256 + r0s) * K_DIM + c0s * 16;
    const char* bS1 = qw + (size_t)(bn * 256 + r1s) * K_DIM + c1s * 16;
    const int ldsC0 = ci0 * 16, ldsC1 = ci1 * 16;

#define SLOT_A(par, h) ((par) * 65536 + (h) * 16384)
#define SLOT_B(par, h) ((par) * 65536 + 32768 + (h) * 16384)
#define STAGE_A(par, h, t) do {                                              \
    cp16(lds + SLOT_A(par, h) + ldsC0,                                       \
         aS0 + (size_t)(h) * 128 * K_DIM + (size_t)(t) * 128);               \
    cp16(lds + SLOT_A(par, h) + ldsC1,                                       \
         aS1 + (size_t)(h) * 128 * K_DIM + (size_t)(t) * 128); } while (0)
#define STAGE_B(par, h, t) do {                                              \
    cp16(lds + SLOT_B(par, h) + ldsC0,                                       \
         bS0 + (size_t)(h) * 128 * K_DIM + (size_t)(t) * 128);               \
    cp16(lds + SLOT_B(par, h) + ldsC1,                                       \
         bS1 + (size_t)(h) * 128 * K_DIM + (size_t)(t) * 128); } while (0)

#define BAR()   __builtin_amdgcn_s_barrier()
#define FENCE() asm volatile("" ::: "memory")

    // fragment read offsets (within parity region)
    const int ch0 = (lg ^ (ln & 7)) * 16;   // k-step 0 swizzled chunk byte
    const int aRd = wm * 16384 + ln * 128;              // + mt*2048
    const int bRd = 32768 + wn * 8192 + ln * 128;       // + nt*2048

    v4i acc[8][4] = {};

    // ---- prologue: stage tile 0 fully, drain, barrier
    STAGE_A(0, 0, 0); STAGE_A(0, 1, 0);
    STAGE_B(0, 0, 0); STAGE_B(0, 1, 0);
    asm volatile("s_waitcnt vmcnt(0)" ::: "memory");
    BAR(); FENCE();

    for (int t = 0; t < NT; ++t) {
        const int par  = t & 1;
        const int base = par << 16;

        // stage next tile into the other parity (free slot since t-1's
        // boundary barrier); issued first so HBM latency hides under the
        // whole tile's compute.
        if (t + 1 < NT) {
            STAGE_A(par ^ 1, 0, t + 1); STAGE_A(par ^ 1, 1, t + 1);
            STAGE_B(par ^ 1, 0, t + 1); STAGE_B(par ^ 1, 1, t + 1);
        }

        // free-run: reads + MFMAs, no barriers; compiler emits counted
        // lgkmcnt so each wave's MFMAs start as soon as its operands land.
#pragma unroll
        for (int ks = 0; ks < 2; ++ks) {
            const int ch = ch0 ^ (ks << 6);
            v4i afr[8], bfr[4];
#pragma unroll
            for (int m = 0; m < 8; ++m)
                afr[m] = *(const v4i*)(lds + base + aRd + m * 2048 + ch);
#pragma unroll
            for (int n = 0; n < 4; ++n)
                bfr[n] = *(const v4i*)(lds + base + bRd + n * 2048 + ch);
            __builtin_amdgcn_s_setprio(1);
#pragma unroll
            for (int m = 0; m < 8; ++m)
#pragma unroll
                for (int n = 0; n < 4; ++n)
                    acc[m][n] = __builtin_amdgcn_mfma_i32_16x16x64_i8(
                        afr[m], bfr[n], acc[m][n], 0, 0, 0);
            __builtin_amdgcn_s_setprio(0);
        }

        // drain t+1's stages (issued ~a full tile ago -> ~free), then the
        // single per-tile barrier.
        asm volatile("s_waitcnt vmcnt(0)" ::: "memory");
        BAR(); FENCE();
    }

    // ---- epilogue (proven). C/D (16x16): col = lane&15, row = lg*4 + reg.
    const int m_base = bm * 256 + wm * 128;
    const int n_base = bn * 256 + wn * 64;

    float sxr[8][4];
#pragma unroll
    for (int m = 0; m < 8; ++m)
#pragma unroll
        for (int r = 0; r < 4; ++r)
            sxr[m][r] = sx[m_base + m * 16 + lg * 4 + r];

#pragma unroll
    for (int n = 0; n < 4; ++n) {
        const int col = n_base + n * 16 + ln;
        const float swv = sw[col];
        const float bv  = bias[col];
#pragma unroll
        for (int m = 0; m < 8; ++m) {
            const int row = m_base + m * 16 + lg * 4;
#pragma unroll
            for (int r = 0; r < 4; ++r) {
                y[(size_t)(row + r) * N_DIM + col] =
                    (float)acc[m][n][r] * sxr[m][r] * swv + bv;
            }
        }
    }
#undef SLOT_A
#undef SLOT_B
#undef STAGE_A
#undef STAGE_B
#undef BAR
#undef FENCE
}

extern "C" void kernel_launch(void* const* d_in, const int* in_sizes, int n_in,
                              void* d_out, int out_size, void* d_ws, size_t ws_size,
                              hipStream_t stream) {
    const float* x = (const float*)d_in[0];   // [B*S, 4096] = [8192, 4096]
    const float* w = (const float*)d_in[1];   // [4096, 4096]
    const float* b = (const float*)d_in[2];   // [4096]
    float* y = (float*)d_out;                 // [8192, 4096]

    const int M = in_sizes[0] / K_DIM;        // 8192
    const int O = in_sizes[1] / K_DIM;        // 4096

    // Workspace layout
    char* qx = (char*)d_ws;                           // M*4096 int8
    char* qw = qx + (size_t)M * K_DIM;                // O*4096 int8
    float* sx = (float*)(qw + (size_t)O * K_DIM);     // M floats
    float* sw = sx + M;                               // O floats

    quant_rows_kernel<<<M + O, 256, 0, stream>>>(x, w, M, qx, qw, sx, sw);

    dim3 grid(N_DIM / 256, M / 256);                  // (16, 32) = 512 blocks
    gemm_i8_kernel<<<grid, 512, 0, stream>>>(qx, qw, sx, sw, b, y);
}

// Round 6
// 384.479 us; speedup vs baseline: 1.0010x; 1.0010x over previous
//
#include <hip/hip_runtime.h>
#include <hip/hip_bf16.h>

// y = (fq_per_token(x) @ fq_per_channel(w)^T) + b
// Exact int8 factorization: y[m,n] = sx[m]*sw[n]*dot_i32(qx[m,:],qw[n,:]) + b[n]

#define K_DIM 4096
#define N_DIM 4096
#define NT (K_DIM / 128)   // 32 K-tiles of 128 bytes

typedef int v4i __attribute__((ext_vector_type(4)));

__device__ __forceinline__ void cp16(void* lds, const void* g) {
    __builtin_amdgcn_global_load_lds(
        (const __attribute__((address_space(1))) void*)g,
        (__attribute__((address_space(3))) void*)lds, 16, 0, 0);
}

// ---------------------------------------------------------------------------
// Per-row symmetric int8 fake-quant, x and w merged into one grid.
// Round-6 change: ONE reciprocal per thread (qs = 1/scale) instead of 16
// fp32 divides (non-fast-math v_div sequence ~15cy each). sdst keeps the
// exact scale. Tie-point rint flips vs x/scale are measure-zero on random
// data and perturb y by ~4e-3 << absmax margin.
// ---------------------------------------------------------------------------
__global__ __launch_bounds__(256) void quant_rows_kernel(
    const float* __restrict__ x, const float* __restrict__ w, int M,
    char* __restrict__ qx, char* __restrict__ qw,
    float* __restrict__ sx, float* __restrict__ sw) {
    const int blk = blockIdx.x;
    const bool is_x = blk < M;
    const int row = is_x ? blk : blk - M;
    const float* rp = (is_x ? x : w) + (size_t)row * 4096;
    char* qdst = is_x ? qx : qw;
    float* sdst = is_x ? sx : sw;

    const int tid = threadIdx.x;

    float4 v[4];
#pragma unroll
    for (int i = 0; i < 4; ++i)
        v[i] = *(const float4*)(rp + 4 * (tid + 256 * i));

    float m = 0.0f;
#pragma unroll
    for (int i = 0; i < 4; ++i) {
        m = fmaxf(m, fmaxf(fmaxf(fabsf(v[i].x), fabsf(v[i].y)),
                           fmaxf(fabsf(v[i].z), fabsf(v[i].w))));
    }
#pragma unroll
    for (int off = 32; off > 0; off >>= 1)
        m = fmaxf(m, __shfl_down(m, off));

    __shared__ float red[4];
    if ((tid & 63) == 0) red[tid >> 6] = m;
    __syncthreads();
    const float amax = fmaxf(fmaxf(red[0], red[1]), fmaxf(red[2], red[3]));
    const float scale = fmaxf(amax / 127.0f, 1e-8f);
    const float qs = 1.0f / scale;   // one divide; then 16 multiplies

    int* qout = (int*)(qdst + (size_t)row * 4096);
#pragma unroll
    for (int i = 0; i < 4; ++i) {
        int q0 = (int)fminf(fmaxf(rintf(v[i].x * qs), -128.0f), 127.0f);
        int q1 = (int)fminf(fmaxf(rintf(v[i].y * qs), -128.0f), 127.0f);
        int q2 = (int)fminf(fmaxf(rintf(v[i].z * qs), -128.0f), 127.0f);
        int q3 = (int)fminf(fmaxf(rintf(v[i].w * qs), -128.0f), 127.0f);
        qout[tid + 256 * i] =
            (q0 & 255) | ((q1 & 255) << 8) | ((q2 & 255) << 16) | ((q3 & 255) << 24);
    }
    if (tid == 0) sdst[row] = scale;
}

// ---------------------------------------------------------------------------
// int8 GEMM, 256x256 tile, 8 waves (2M x 4N), BK = 128 bytes, free-run loop
// (1 barrier per K-tile, round-5 structure).
//
// Round-6 change: WAVE-GROUP K-STEP STAGGER. Evidence: rounds 1-5 all land
// at ~5000-5200 cy/tile = MFMA floor (2611) + LDS window (~2400) SERIAL;
// removing barriers (r5) barely helped, so the serializer is that both
// waves resident on a SIMD (waves s and s+4) are phase-aligned: both burst
// ds_reads, then both MFMA -> LDS and MFMA pipes alternate instead of
// overlapping. Fix: waves 0-3 process k-steps (0,1); waves 4-7 process
// (1,0). Integer accumulation commutes exactly and both k-steps are staged
// together, so order is free. Now each SIMD always has one wave reading
// while the other MFMAs (m114 cross-wave overlap), and setprio has a real
// role-split to arbitrate (m218b mechanism). Target: per-tile ->
// ~max(MFMA, LDS) + residual ~ 3200-3600 cy.
//
// Per tile t: [BAR] stage A,B(t+1)->par^1 (8 cp16) ; for ks2 in {0,1}:
// {12 ds_read_b128(par, ks2^ksf) ; 32 MFMA} ; vmcnt(0) ; [BAR].
//   RAW: t's reads hit data staged in t-1, drained by t-1's vmcnt(0).
//   WAR: stages write par^1, last read in t-1 before t-1's MFMAs issued.
//   vmcnt(0) at end of t: only in-flight loads are t+1's stages, issued a
//   full tile (~2700 cy) earlier -> ~free.
//
// LDS swizzle (proven, 0 conflicts): 16B chunk c of row r stored at
// c ^ (r&7); fragment read chunk = (ks*4 + lg) ^ (ln&7).
// ---------------------------------------------------------------------------
__global__ __launch_bounds__(512, 2) void gemm_i8_kernel(
    const char* __restrict__ qx, const char* __restrict__ qw,
    const float* __restrict__ sx, const float* __restrict__ sw,
    const float* __restrict__ bias, float* __restrict__ y) {

    __shared__ __align__(16) char lds[131072];

    const int tid  = threadIdx.x;
    const int wave = tid >> 6;
    const int lane = tid & 63;
    const int ln   = lane & 15;   // MFMA column index
    const int lg   = lane >> 4;   // MFMA lane-group 0..3
    const int wm   = wave >> 2;   // wave tile m (0..1) -> rows wm*128..+127
    const int wn   = wave & 3;    // wave tile n (0..3) -> cols wn*64..+63
    const int ksf  = (wave >> 2) & 1;  // k-step stagger: SIMD-mates differ

    const int bm = blockIdx.y;
    const int bn = blockIdx.x;

    // staging: thread t handles 16B chunks t and t+512 of each 128-row half
    // (wave-contiguous LDS dest for global_load_lds); global source
    // pre-swizzled so LDS chunk (r, c) holds global k-chunk c ^ (r&7).
    const int ci0 = tid,       r0s = ci0 >> 3, c0s = (ci0 & 7) ^ (r0s & 7);
    const int ci1 = tid + 512, r1s = ci1 >> 3, c1s = (ci1 & 7) ^ (r1s & 7);
    const char* aS0 = qx + (size_t)(bm * 256 + r0s) * K_DIM + c0s * 16;
    const char* aS1 = qx + (size_t)(bm * 256 + r1s) * K_DIM + c1s * 16;
    const char* bS0 = qw + (size_t)(bn * 256 + r0s) * K_DIM + c0s * 16;
    const char* bS1 = qw + (size_t)(bn * 256 + r1s) * K_DIM + c1s * 16;
    const int ldsC0 = ci0 * 16, ldsC1 = ci1 * 16;

#define SLOT_A(par, h) ((par) * 65536 + (h) * 16384)
#define SLOT_B(par, h) ((par) * 65536 + 32768 + (h) * 16384)
#define STAGE_A(par, h, t) do {                                              \
    cp16(lds + SLOT_A(par, h) + ldsC0,                                       \
         aS0 + (size_t)(h) * 128 * K_DIM + (size_t)(t) * 128);               \
    cp16(lds + SLOT_A(par, h) + ldsC1,                                       \
         aS1 + (size_t)(h) * 128 * K_DIM + (size_t)(t) * 128); } while (0)
#define STAGE_B(par, h, t) do {                                              \
    cp16(lds + SLOT_B(par, h) + ldsC0,                                       \
         bS0 + (size_t)(h) * 128 * K_DIM + (size_t)(t) * 128);               \
    cp16(lds + SLOT_B(par, h) + ldsC1,                                       \
         bS1 + (size_t)(h) * 128 * K_DIM + (size_t)(t) * 128); } while (0)

#define BAR()   __builtin_amdgcn_s_barrier()
#define FENCE() asm volatile("" ::: "memory")

    // fragment read offsets (within parity region)
    const int ch0 = (lg ^ (ln & 7)) * 16;   // k-step 0 swizzled chunk byte
    const int aRd = wm * 16384 + ln * 128;              // + mt*2048
    const int bRd = 32768 + wn * 8192 + ln * 128;       // + nt*2048

    v4i acc[8][4] = {};

    // ---- prologue: stage tile 0 fully, drain, barrier
    STAGE_A(0, 0, 0); STAGE_A(0, 1, 0);
    STAGE_B(0, 0, 0); STAGE_B(0, 1, 0);
    asm volatile("s_waitcnt vmcnt(0)" ::: "memory");
    BAR(); FENCE();

    for (int t = 0; t < NT; ++t) {
        const int par  = t & 1;
        const int base = par << 16;

        // stage next tile into the other parity; issued first so HBM
        // latency hides under the whole tile's compute.
        if (t + 1 < NT) {
            STAGE_A(par ^ 1, 0, t + 1); STAGE_A(par ^ 1, 1, t + 1);
            STAGE_B(par ^ 1, 0, t + 1); STAGE_B(par ^ 1, 1, t + 1);
        }

        // free-run with per-wave-group k-step order (ks2 ^ ksf): SIMD-mates
        // are always in opposite halves -> LDS reads overlap MFMA.
#pragma unroll
        for (int ks2 = 0; ks2 < 2; ++ks2) {
            const int ch = ch0 ^ (((ks2 ^ ksf) & 1) << 6);
            v4i afr[8], bfr[4];
#pragma unroll
            for (int m = 0; m < 8; ++m)
                afr[m] = *(const v4i*)(lds + base + aRd + m * 2048 + ch);
#pragma unroll
            for (int n = 0; n < 4; ++n)
                bfr[n] = *(const v4i*)(lds + base + bRd + n * 2048 + ch);
            __builtin_amdgcn_s_setprio(1);
#pragma unroll
            for (int m = 0; m < 8; ++m)
#pragma unroll
                for (int n = 0; n < 4; ++n)
                    acc[m][n] = __builtin_amdgcn_mfma_i32_16x16x64_i8(
                        afr[m], bfr[n], acc[m][n], 0, 0, 0);
            __builtin_amdgcn_s_setprio(0);
        }

        // drain t+1's stages (issued ~a full tile ago -> ~free), then the
        // single per-tile barrier.
        asm volatile("s_waitcnt vmcnt(0)" ::: "memory");
        BAR(); FENCE();
    }

    // ---- epilogue (proven). C/D (16x16): col = lane&15, row = lg*4 + reg.
    const int m_base = bm * 256 + wm * 128;
    const int n_base = bn * 256 + wn * 64;

    float sxr[8][4];
#pragma unroll
    for (int m = 0; m < 8; ++m)
#pragma unroll
        for (int r = 0; r < 4; ++r)
            sxr[m][r] = sx[m_base + m * 16 + lg * 4 + r];

#pragma unroll
    for (int n = 0; n < 4; ++n) {
        const int col = n_base + n * 16 + ln;
        const float swv = sw[col];
        const float bv  = bias[col];
#pragma unroll
        for (int m = 0; m < 8; ++m) {
            const int row = m_base + m * 16 + lg * 4;
#pragma unroll
            for (int r = 0; r < 4; ++r) {
                y[(size_t)(row + r) * N_DIM + col] =
                    (float)acc[m][n][r] * sxr[m][r] * swv + bv;
            }
        }
    }
#undef SLOT_A
#undef SLOT_B
#undef STAGE_A
#undef STAGE_B
#undef BAR
#undef FENCE
}

extern "C" void kernel_launch(void* const* d_in, const int* in_sizes, int n_in,
                              void* d_out, int out_size, void* d_ws, size_t ws_size,
                              hipStream_t stream) {
    const float* x = (const float*)d_in[0];   // [B*S, 4096] = [8192, 4096]
    const float* w = (const float*)d_in[1];   // [4096, 4096]
    const float* b = (const float*)d_in[2];   // [4096]
    float* y = (float*)d_out;                 // [8192, 4096]

    const int M = in_sizes[0] / K_DIM;        // 8192
    const int O = in_sizes[1] / K_DIM;        // 4096

    // Workspace layout
    char* qx = (char*)d_ws;                           // M*4096 int8
    char* qw = qx + (size_t)M * K_DIM;                // O*4096 int8
    float* sx = (float*)(qw + (size_t)O * K_DIM);     // M floats
    float* sw = sx + M;                               // O floats

    quant_rows_kernel<<<M + O, 256, 0, stream>>>(x, w, M, qx, qw, sx, sw);

    dim3 grid(N_DIM / 256, M / 256);                  // (16, 32) = 512 blocks
    gemm_i8_kernel<<<grid, 512, 0, stream>>>(qx, qw, sx, sw, b, y);
}